// Round 3
// baseline (1549.405 us; speedup 1.0000x reference)
//
#include <hip/hip_runtime.h>
#include <cstddef>

#define L_SEQ 1024
#define B_SZ  128
#define D_SZ  256
#define H_SZ  256

#define NSCAN 128
#define NGEMM 2048            // 1024 tm tiles x 2 tn tiles

// ---------------------------------------------------------------------------
// Fused producer-consumer kernel.
//   blocks [0, 128)         : scan role, one batch element each (consumer)
//   blocks [128, 128+2048)  : xproj GEMM tiles (producer); tile tm covers
//                             timestep l = tm entirely (rows l*B..l*B+127).
// GEMM signals done[tm] (2 increments = both tn tiles) after
// __threadfence_system, so data is in L3/HBM. Scan polls done[] and reads
// xproj with RELAXED SYSTEM-scope loads (sc0 sc1 -> bypass possibly-stale
// per-XCD L2; no buffer_inv, no vmcnt(0) drain on the critical path).
// ---------------------------------------------------------------------------

#define KT  16
#define LDA 132
#define SLICE_W 40

typedef float f2 __attribute__((ext_vector_type(2)));

#define PKFMA(acc, w, h) \
    asm("v_pk_fma_f32 %0, %1, %2, %0" : "+v"(acc) : "v"(w), "v"(h))

template <int CTRL>
__device__ __forceinline__ float dpp_add(float v) {
    int y = __builtin_amdgcn_mov_dpp(__float_as_int(v), CTRL, 0xf, 0xf, true);
    return v + __int_as_float(y);
}
// Full butterfly over the 8 lanes of a ks-group (pure VALU, valid all lanes).
__device__ __forceinline__ float red8(f2 a) {
    float v = a.x + a.y;
    v = dpp_add<0xB1>(v);     // quad_perm xor 1
    v = dpp_add<0x4E>(v);     // quad_perm xor 2
    v = dpp_add<0x141>(v);    // row_half_mirror (xor 7)
    return v;
}
__device__ __forceinline__ float fast_tanh(float x) {
    float e = __expf(2.0f * x);
    return 1.0f - 2.0f * __builtin_amdgcn_rcpf(e + 1.0f);
}
// Barrier that does NOT drain vmcnt: only LDS ordering is required.
__device__ __forceinline__ void lds_barrier() {
    asm volatile("s_waitcnt lgkmcnt(0)" ::: "memory");
    __builtin_amdgcn_s_barrier();
    asm volatile("" ::: "memory");
}
__device__ __forceinline__ float sysloadf(const float* p) {
    return __hip_atomic_load(p, __ATOMIC_RELAXED, __HIP_MEMORY_SCOPE_SYSTEM);
}
__device__ __forceinline__ int sysloadi(const int* p) {
    return __hip_atomic_load(p, __ATOMIC_RELAXED, __HIP_MEMORY_SCOPE_SYSTEM);
}

// ---------------------------------------------------------------------------
// GEMM role: 512 threads, 128x128 tile, KT=16.
// ---------------------------------------------------------------------------
__device__ __forceinline__ void gemm_role(
    int gb,
    const float* __restrict__ x, const float* __restrict__ Wx,
    const float* __restrict__ bx, const float* __restrict__ bh,
    float* __restrict__ out, int* __restrict__ done,
    float (*sA)[LDA], float (*sB)[LDA])
{
    const int tm  = gb >> 1;
    const int tn  = gb & 1;
    const int tid = threadIdx.x;
    const int tx  = tid & 15;        // col quad 0..15
    const int ty  = tid >> 4;        // row quad 0..31
    const int srow = tid >> 2;       // 0..127
    const int skq  = tid & 3;        // 0..3

    const float* __restrict__ Ag = x  + (size_t)(tm * 128 + srow) * D_SZ + skq * 4;
    const float* __restrict__ Bg = Wx + (size_t)(tn * 128 + srow) * D_SZ + skq * 4;

    float c[2][4][4];
    #pragma unroll
    for (int nc = 0; nc < 2; ++nc)
        #pragma unroll
        for (int i = 0; i < 4; ++i)
            #pragma unroll
            for (int j = 0; j < 4; ++j) c[nc][i][j] = 0.0f;

    for (int kt = 0; kt < D_SZ / KT; ++kt) {
        float4 av = *reinterpret_cast<const float4*>(Ag + kt * KT);
        float4 bv = *reinterpret_cast<const float4*>(Bg + kt * KT);
        __syncthreads();
        sA[skq * 4 + 0][srow] = av.x; sA[skq * 4 + 1][srow] = av.y;
        sA[skq * 4 + 2][srow] = av.z; sA[skq * 4 + 3][srow] = av.w;
        sB[skq * 4 + 0][srow] = bv.x; sB[skq * 4 + 1][srow] = bv.y;
        sB[skq * 4 + 2][srow] = bv.z; sB[skq * 4 + 3][srow] = bv.w;
        __syncthreads();
        #pragma unroll
        for (int kk = 0; kk < KT; ++kk) {
            float4 am  = *reinterpret_cast<const float4*>(&sA[kk][ty * 4]);
            float4 bn0 = *reinterpret_cast<const float4*>(&sB[kk][tx * 4]);
            float4 bn1 = *reinterpret_cast<const float4*>(&sB[kk][64 + tx * 4]);
            float aa[4] = {am.x, am.y, am.z, am.w};
            float bb[2][4] = {{bn0.x, bn0.y, bn0.z, bn0.w},
                              {bn1.x, bn1.y, bn1.z, bn1.w}};
            #pragma unroll
            for (int nc = 0; nc < 2; ++nc)
                #pragma unroll
                for (int i = 0; i < 4; ++i)
                    #pragma unroll
                    for (int j = 0; j < 4; ++j)
                        c[nc][i][j] = fmaf(aa[i], bb[nc][j], c[nc][i][j]);
        }
    }

    #pragma unroll
    for (int nc = 0; nc < 2; ++nc) {
        const int col = tn * 128 + nc * 64 + tx * 4;
        float4 b4 = *reinterpret_cast<const float4*>(bx + col);
        float4 h4 = *reinterpret_cast<const float4*>(bh + col);   // fold Wh bias
        #pragma unroll
        for (int i = 0; i < 4; ++i) {
            float4 v;
            v.x = c[nc][i][0] + b4.x + h4.x;
            v.y = c[nc][i][1] + b4.y + h4.y;
            v.z = c[nc][i][2] + b4.z + h4.z;
            v.w = c[nc][i][3] + b4.w + h4.w;
            *reinterpret_cast<float4*>(
                out + (size_t)(tm * 128 + ty * 4 + i) * H_SZ + col) = v;
        }
    }

    // Publish: data to L3/HBM, then flag.
    __threadfence_system();
    __syncthreads();
    if (tid == 0) {
        __hip_atomic_fetch_add(&done[tm], 1, __ATOMIC_RELEASE,
                               __HIP_MEMORY_SCOPE_SYSTEM);
    }
}

// ---------------------------------------------------------------------------
// Scan role (v8 = v7 + producer polls, bias folded out, setprio(1)).
// ---------------------------------------------------------------------------
#define DECLQ(c, q) \
    f2 w##c##_##q##l = r##c[2 * (q)], w##c##_##q##h = r##c[2 * (q) + 1];
#define DECLC(c) \
    DECLQ(c,0) DECLQ(c,1) DECLQ(c,2) DECLQ(c,3) \
    DECLQ(c,4) DECLQ(c,5) DECLQ(c,6) DECLQ(c,7)

#define FMAQ(q) { \
    float4 hv = hv4[q]; \
    f2 hlo = {hv.x, hv.y}; \
    f2 hhi = {hv.z, hv.w}; \
    PKFMA(a0, w0_##q##l, hlo); PKFMA(a0, w0_##q##h, hhi); \
    PKFMA(a1, w1_##q##l, hlo); PKFMA(a1, w1_##q##h, hhi); \
    PKFMA(a2, w2_##q##l, hlo); PKFMA(a2, w2_##q##h, hhi); \
    PKFMA(a3, w3_##q##l, hlo); PKFMA(a3, w3_##q##h, hhi); }

// One scan step. Poll protocol:
//  - apply lookahead results issued LAST body (branch waits on loads ~1 full
//    body old -> tiny vmcnt wait, and vmcnt(4): xp prefetches stay in flight)
//  - cold spin only if hw < need (steady state: scalar compare, no memory op)
//  - issue NEXT lookahead polls BEFORE the xp prefetch loads (so next body's
//    consumption waits at vmcnt(4), not vmcnt(0))
#define SBODY(T, SRC, DST, X0, X1, X2, X3) { \
    if (la0 == 2) { ++hw; if (la1 == 2) ++hw; } \
    const int tnext = ((T) + 2 < L_SEQ) ? (T) + 2 : L_SEQ - 1; \
    { const int need = tnext + 1; \
      while (hw < need) { \
        int d = sysloadi(&done[hw]); \
        if (d == 2) ++hw; else __builtin_amdgcn_s_sleep(2); \
      } } \
    asm volatile("" ::: "memory"); \
    la0 = 0; la1 = 0; \
    if (hw < L_SEQ)     la0 = sysloadi(&done[hw]); \
    if (hw + 1 < L_SEQ) la1 = sysloadi(&done[hw + 1]); \
    float u0 = X0, u1 = X1, u2 = X2, u3 = X3; \
    { const size_t t2 = (size_t)tnext * tstr; \
      X0 = sysloadf(&outb[t2 + jg +   0]); \
      X1 = sysloadf(&outb[t2 + jg +  64]); \
      X2 = sysloadf(&outb[t2 + jg + 128]); \
      X3 = sysloadf(&outb[t2 + jg + 192]); } \
    f2 a0 = {0.f, 0.f}, a1 = {0.f, 0.f}, a2 = {0.f, 0.f}, a3 = {0.f, 0.f}; \
    const float4* hv4 = reinterpret_cast<const float4*>(&hs[SRC][ks * SLICE_W]); \
    FMAQ(0) FMAQ(1) FMAQ(2) FMAQ(3) FMAQ(4) FMAQ(5) FMAQ(6) FMAQ(7) \
    float s0 = red8(a0); \
    float s1 = red8(a1); \
    float s2 = red8(a2); \
    float s3 = red8(a3); \
    hn0 = fast_tanh(u0 + s0); \
    hn1 = fast_tanh(u1 + s1); \
    hn2 = fast_tanh(u2 + s2); \
    hn3 = fast_tanh(u3 + s3); \
    if (ks == 0) { \
        const size_t tb = (size_t)(T) * tstr; \
        __builtin_nontemporal_store(hn0, &outb[tb + jg +   0]); \
        __builtin_nontemporal_store(hn1, &outb[tb + jg +  64]); \
        __builtin_nontemporal_store(hn2, &outb[tb + jg + 128]); \
        __builtin_nontemporal_store(hn3, &outb[tb + jg + 192]); \
        float* hptr = hs[DST]; \
        const int base = (jg >> 5) * SLICE_W + (jg & 31); \
        hptr[base + 0 * (2 * SLICE_W)] = hn0; \
        hptr[base + 1 * (2 * SLICE_W)] = hn1; \
        hptr[base + 2 * (2 * SLICE_W)] = hn2; \
        hptr[base + 3 * (2 * SLICE_W)] = hn3; \
    } \
    lds_barrier(); \
}

__device__ __forceinline__ void scan_role(
    int b,
    const float* __restrict__ h0, const float* __restrict__ Wh,
    float* __restrict__ out, int* __restrict__ done,
    float (*hs)[8 * SLICE_W])
{
    __builtin_amdgcn_s_setprio(1);   // favor scan waves over co-resident GEMM

    const int tid  = threadIdx.x;
    const int lane = tid & 63;
    const int wave = tid >> 6;
    const int ks   = lane & 7;                 // K slice 0..7
    const int jg   = wave * 8 + (lane >> 3);   // channel group 0..63

    const f2* r0 = reinterpret_cast<const f2*>(Wh + (size_t)(jg +   0) * H_SZ + ks * 32);
    const f2* r1 = reinterpret_cast<const f2*>(Wh + (size_t)(jg +  64) * H_SZ + ks * 32);
    const f2* r2 = reinterpret_cast<const f2*>(Wh + (size_t)(jg + 128) * H_SZ + ks * 32);
    const f2* r3 = reinterpret_cast<const f2*>(Wh + (size_t)(jg + 192) * H_SZ + ks * 32);
    DECLC(0) DECLC(1) DECLC(2) DECLC(3)

    if (tid < H_SZ) {
        hs[0][(tid >> 5) * SLICE_W + (tid & 31)] = h0[(size_t)b * H_SZ + tid];
    }
    __syncthreads();

    float* __restrict__ outb = out + (size_t)b * H_SZ;
    const size_t tstr = (size_t)B_SZ * H_SZ;

    int hw = 0, la0 = 0, la1 = 0;
    // cold-start: need slabs 0,1 for prologue loads
    while (hw < 2) {
        int d = sysloadi(&done[hw]);
        if (d == 2) ++hw; else __builtin_amdgcn_s_sleep(8);
    }
    asm volatile("" ::: "memory");

    float xa0 = sysloadf(&outb[jg +   0]);
    float xa1 = sysloadf(&outb[jg +  64]);
    float xa2 = sysloadf(&outb[jg + 128]);
    float xa3 = sysloadf(&outb[jg + 192]);
    float xb0 = sysloadf(&outb[tstr + jg +   0]);
    float xb1 = sysloadf(&outb[tstr + jg +  64]);
    float xb2 = sysloadf(&outb[tstr + jg + 128]);
    float xb3 = sysloadf(&outb[tstr + jg + 192]);

    float hn0 = 0.f, hn1 = 0.f, hn2 = 0.f, hn3 = 0.f;
    for (int t = 0; t < L_SEQ; t += 2) {
        SBODY(t,     0, 1, xa0, xa1, xa2, xa3)
        SBODY(t + 1, 1, 0, xb0, xb1, xb2, xb3)
    }

    if (ks == 0) {
        float* hf = out + (size_t)L_SEQ * tstr + (size_t)b * H_SZ;
        hf[jg +   0] = hn0;
        hf[jg +  64] = hn1;
        hf[jg + 128] = hn2;
        hf[jg + 192] = hn3;
    }
}

// ---------------------------------------------------------------------------
// Fused kernel
// ---------------------------------------------------------------------------
__global__ __launch_bounds__(512) void rnn_fused(
    const float* __restrict__ x,  const float* __restrict__ h0,
    const float* __restrict__ Wx, const float* __restrict__ bx,
    const float* __restrict__ Wh, const float* __restrict__ bh,
    float* __restrict__ out, int* __restrict__ done)
{
    __shared__ float sA[KT][LDA];
    __shared__ float sB[KT][LDA];
    __shared__ __align__(16) float hs[2][8 * SLICE_W];

    const int bid = blockIdx.x;
    if (bid < NSCAN) {
        scan_role(bid, h0, Wh, out, done, hs);
    } else {
        gemm_role(bid - NSCAN, x, Wx, bx, bh, out, done, sA, sB);
    }
}

extern "C" void kernel_launch(void* const* d_in, const int* in_sizes, int n_in,
                              void* d_out, int out_size, void* d_ws, size_t ws_size,
                              hipStream_t stream) {
    const float* x    = (const float*)d_in[0];   // [L,B,D]
    const float* h0   = (const float*)d_in[1];   // [B,H]
    const float* Wx_w = (const float*)d_in[2];   // [H,D]
    const float* Wx_b = (const float*)d_in[3];   // [H]
    const float* Wh_w = (const float*)d_in[4];   // [H,H]
    const float* Wh_b = (const float*)d_in[5];   // [H]
    float* out = (float*)d_out;                  // [L,B,H] ++ [B,H]
    int* done = (int*)d_ws;                      // [L_SEQ] tile-completion flags

    (void)in_sizes; (void)n_in; (void)ws_size; (void)out_size;

    // Re-arm flags every iteration (graph-safe stream op).
    hipMemsetAsync(done, 0, L_SEQ * sizeof(int), stream);

    rnn_fused<<<dim3(NSCAN + NGEMM), 512, 0, stream>>>(
        x, h0, Wx_w, Wx_b, Wh_w, Wh_b, out, done);
}

// Round 5
// 1097.630 us; speedup vs baseline: 1.4116x; 1.4116x over previous
//
#include <hip/hip_runtime.h>
#include <cstddef>

#define L_SEQ 1024
#define B_SZ  128
#define D_SZ  256
#define H_SZ  256

typedef float f2 __attribute__((ext_vector_type(2)));

// ---------------------------------------------------------------------------
// v_pk_fma_f32 helpers.
// PKFMA: plain packed fma (acc += w * h), both operands full pairs.
// PKFMA_LO/HI: broadcast src0's lo/hi element into both halves via op_sel
// (VOP3P: op_sel bit = element for lo half, op_sel_hi bit = element for hi
//  half). Lets a b128-loaded float4 {x,y,z,w} feed scalar broadcasts with
// ZERO duplicate v_movs: pairs {x,y},{z,w} are even-aligned subregisters.
// ---------------------------------------------------------------------------
#define PKFMA(acc, w, h) \
    asm("v_pk_fma_f32 %0, %1, %2, %0" : "+v"(acc) : "v"(w), "v"(h))
#define PKFMA_LO(acc, ap, b) \
    asm("v_pk_fma_f32 %0, %1, %2, %0 op_sel:[0,0,0] op_sel_hi:[0,1,1]" \
        : "+v"(acc) : "v"(ap), "v"(b))
#define PKFMA_HI(acc, ap, b) \
    asm("v_pk_fma_f32 %0, %1, %2, %0 op_sel:[1,0,0] op_sel_hi:[1,1,1]" \
        : "+v"(acc) : "v"(ap), "v"(b))

// ---------------------------------------------------------------------------
// Kernel 1: xproj GEMM, v2 = R2 structure + packed-FP32 inner loop
// (36 instr/kk instead of 68 for the same 64 FMAs) + Wh_b folded into the
// epilogue so the scan kernel drops its per-step bias adds.
// ---------------------------------------------------------------------------
#define KT  16
#define LDA 132

#define ROWFMA(ap, PK, M, I) \
    PK(c2[M][0][I][0], ap, b00); PK(c2[M][0][I][1], ap, b01); \
    PK(c2[M][1][I][0], ap, b10); PK(c2[M][1][I][1], ap, b11);

__global__ __launch_bounds__(256) void xproj_gemm(
    const float* __restrict__ x, const float* __restrict__ Wx,
    const float* __restrict__ bx, const float* __restrict__ bh,
    float* __restrict__ out)
{
    __shared__ float sA[KT][LDA];
    __shared__ float sB[KT][LDA];

    const int tm  = blockIdx.x;
    const int tn  = blockIdx.y;
    const int tid = threadIdx.x;
    const int tx  = tid & 15;
    const int ty  = tid >> 4;
    const int srow = tid >> 2;
    const int skq  = tid & 3;

    const float* __restrict__ Ag = x  + (size_t)(tm * 128 + srow) * D_SZ + skq * 4;
    const float* __restrict__ Bg = Wx + (size_t)(tn * 128 + srow) * D_SZ + skq * 4;

    f2 c2[2][2][4][2];   // [mc][nc][i][jpair]
    #pragma unroll
    for (int mc = 0; mc < 2; ++mc)
        #pragma unroll
        for (int nc = 0; nc < 2; ++nc)
            #pragma unroll
            for (int i = 0; i < 4; ++i)
                #pragma unroll
                for (int jp = 0; jp < 2; ++jp) c2[mc][nc][i][jp] = (f2){0.f, 0.f};

    for (int kt = 0; kt < D_SZ / KT; ++kt) {
        float4 av0 = *reinterpret_cast<const float4*>(Ag + kt * KT);
        float4 av1 = *reinterpret_cast<const float4*>(Ag + (size_t)64 * D_SZ + kt * KT);
        float4 bv0 = *reinterpret_cast<const float4*>(Bg + kt * KT);
        float4 bv1 = *reinterpret_cast<const float4*>(Bg + (size_t)64 * D_SZ + kt * KT);
        __syncthreads();
        sA[skq * 4 + 0][srow] = av0.x; sA[skq * 4 + 1][srow] = av0.y;
        sA[skq * 4 + 2][srow] = av0.z; sA[skq * 4 + 3][srow] = av0.w;
        sA[skq * 4 + 0][64 + srow] = av1.x; sA[skq * 4 + 1][64 + srow] = av1.y;
        sA[skq * 4 + 2][64 + srow] = av1.z; sA[skq * 4 + 3][64 + srow] = av1.w;
        sB[skq * 4 + 0][srow] = bv0.x; sB[skq * 4 + 1][srow] = bv0.y;
        sB[skq * 4 + 2][srow] = bv0.z; sB[skq * 4 + 3][srow] = bv0.w;
        sB[skq * 4 + 0][64 + srow] = bv1.x; sB[skq * 4 + 1][64 + srow] = bv1.y;
        sB[skq * 4 + 2][64 + srow] = bv1.z; sB[skq * 4 + 3][64 + srow] = bv1.w;
        __syncthreads();
        #pragma unroll
        for (int kk = 0; kk < KT; ++kk) {
            float4 am0 = *reinterpret_cast<const float4*>(&sA[kk][ty * 4]);
            float4 am1 = *reinterpret_cast<const float4*>(&sA[kk][64 + ty * 4]);
            float4 bn0 = *reinterpret_cast<const float4*>(&sB[kk][tx * 4]);
            float4 bn1 = *reinterpret_cast<const float4*>(&sB[kk][64 + tx * 4]);
            f2 a00 = {am0.x, am0.y}, a01 = {am0.z, am0.w};
            f2 a10 = {am1.x, am1.y}, a11 = {am1.z, am1.w};
            f2 b00 = {bn0.x, bn0.y}, b01 = {bn0.z, bn0.w};
            f2 b10 = {bn1.x, bn1.y}, b11 = {bn1.z, bn1.w};
            ROWFMA(a00, PKFMA_LO, 0, 0) ROWFMA(a00, PKFMA_HI, 0, 1)
            ROWFMA(a01, PKFMA_LO, 0, 2) ROWFMA(a01, PKFMA_HI, 0, 3)
            ROWFMA(a10, PKFMA_LO, 1, 0) ROWFMA(a10, PKFMA_HI, 1, 1)
            ROWFMA(a11, PKFMA_LO, 1, 2) ROWFMA(a11, PKFMA_HI, 1, 3)
        }
    }

    #pragma unroll
    for (int nc = 0; nc < 2; ++nc) {
        const int col = tn * 128 + nc * 64 + tx * 4;
        float4 b4 = *reinterpret_cast<const float4*>(bx + col);
        float4 h4 = *reinterpret_cast<const float4*>(bh + col);  // fold Wh bias
        #pragma unroll
        for (int mc = 0; mc < 2; ++mc)
            #pragma unroll
            for (int i = 0; i < 4; ++i) {
                float4 v;
                v.x = c2[mc][nc][i][0].x + b4.x + h4.x;
                v.y = c2[mc][nc][i][0].y + b4.y + h4.y;
                v.z = c2[mc][nc][i][1].x + b4.z + h4.z;
                v.w = c2[mc][nc][i][1].y + b4.w + h4.w;
                *reinterpret_cast<float4*>(
                    out + (size_t)(tm * 128 + mc * 64 + ty * 4 + i) * H_SZ + col) = v;
            }
    }
}

// ---------------------------------------------------------------------------
// Kernel 2: serial scan, v9 = R2's v7 (measured 735 us) minus the per-step
// bias adds (bias folded into GEMM epilogue). Fusion (R3) reverted: GEMM
// co-residency on scan CUs serialized the scan's LDS handoff (4.2M bank
// conflicts, VALUBusy 25%) -- the scan must own its CUs.
// ---------------------------------------------------------------------------
#define SLICE_W 40

template <int CTRL>
__device__ __forceinline__ float dpp_add(float v) {
    int y = __builtin_amdgcn_mov_dpp(__float_as_int(v), CTRL, 0xf, 0xf, true);
    return v + __int_as_float(y);
}
// Full butterfly over the 8 lanes of a ks-group (pure VALU, valid all lanes).
__device__ __forceinline__ float red8(f2 a) {
    float v = a.x + a.y;
    v = dpp_add<0xB1>(v);     // quad_perm xor 1
    v = dpp_add<0x4E>(v);     // quad_perm xor 2
    v = dpp_add<0x141>(v);    // row_half_mirror (xor 7)
    return v;
}
__device__ __forceinline__ float fast_tanh(float x) {
    float e = __expf(2.0f * x);
    return 1.0f - 2.0f * __builtin_amdgcn_rcpf(e + 1.0f);
}
// Barrier that does NOT drain vmcnt: only LDS ordering is required.
__device__ __forceinline__ void lds_barrier() {
    asm volatile("s_waitcnt lgkmcnt(0)" ::: "memory");
    __builtin_amdgcn_s_barrier();
    asm volatile("" ::: "memory");
}

#define DECLQ(c, q) \
    f2 w##c##_##q##l = r##c[2 * (q)], w##c##_##q##h = r##c[2 * (q) + 1];
#define DECLC(c) \
    DECLQ(c,0) DECLQ(c,1) DECLQ(c,2) DECLQ(c,3) \
    DECLQ(c,4) DECLQ(c,5) DECLQ(c,6) DECLQ(c,7)

#define FMAQ(q) { \
    float4 hv = hv4[q]; \
    f2 hlo = {hv.x, hv.y}; \
    f2 hhi = {hv.z, hv.w}; \
    PKFMA(a0, w0_##q##l, hlo); PKFMA(a0, w0_##q##h, hhi); \
    PKFMA(a1, w1_##q##l, hlo); PKFMA(a1, w1_##q##h, hhi); \
    PKFMA(a2, w2_##q##l, hlo); PKFMA(a2, w2_##q##h, hhi); \
    PKFMA(a3, w3_##q##l, hlo); PKFMA(a3, w3_##q##h, hhi); }

// One scan step. X* hold xproj(+biases) for THIS step; after capture into u*,
// the slab for step T+2 is loaded DIRECTLY into them (no copies -> no
// same-iteration vmcnt wait; 2-body prefetch distance).
#define BODY(T, SRC, DST, X0, X1, X2, X3) { \
    float u0 = X0, u1 = X1, u2 = X2, u3 = X3; \
    { \
        const int tnext = (T) + 2 < L_SEQ ? (T) + 2 : L_SEQ - 1; \
        const size_t t2 = (size_t)tnext * tstr; \
        X0 = outb[t2 + jg +   0]; \
        X1 = outb[t2 + jg +  64]; \
        X2 = outb[t2 + jg + 128]; \
        X3 = outb[t2 + jg + 192]; \
    } \
    f2 a0 = {0.f, 0.f}, a1 = {0.f, 0.f}, a2 = {0.f, 0.f}, a3 = {0.f, 0.f}; \
    const float4* hv4 = reinterpret_cast<const float4*>(&hs[SRC][ks * SLICE_W]); \
    FMAQ(0) FMAQ(1) FMAQ(2) FMAQ(3) FMAQ(4) FMAQ(5) FMAQ(6) FMAQ(7) \
    float s0 = red8(a0); \
    float s1 = red8(a1); \
    float s2 = red8(a2); \
    float s3 = red8(a3); \
    hn0 = fast_tanh(u0 + s0); \
    hn1 = fast_tanh(u1 + s1); \
    hn2 = fast_tanh(u2 + s2); \
    hn3 = fast_tanh(u3 + s3); \
    if (ks == 0) { \
        const size_t tb = (size_t)(T) * tstr; \
        __builtin_nontemporal_store(hn0, &outb[tb + jg +   0]); \
        __builtin_nontemporal_store(hn1, &outb[tb + jg +  64]); \
        __builtin_nontemporal_store(hn2, &outb[tb + jg + 128]); \
        __builtin_nontemporal_store(hn3, &outb[tb + jg + 192]); \
        float* hw = hs[DST]; \
        const int base = (jg >> 5) * SLICE_W + (jg & 31); \
        hw[base + 0 * (2 * SLICE_W)] = hn0; \
        hw[base + 1 * (2 * SLICE_W)] = hn1; \
        hw[base + 2 * (2 * SLICE_W)] = hn2; \
        hw[base + 3 * (2 * SLICE_W)] = hn3; \
    } \
    lds_barrier(); \
}

__global__ __launch_bounds__(512)
__attribute__((amdgpu_waves_per_eu(2, 2)))
void rnn_scan(
    const float* __restrict__ h0, const float* __restrict__ Wh,
    float* __restrict__ out)
{
    __shared__ __align__(16) float hs[2][8 * SLICE_W];

    const int b    = blockIdx.x;
    const int tid  = threadIdx.x;
    const int lane = tid & 63;
    const int wave = tid >> 6;
    const int ks   = lane & 7;                 // K slice 0..7
    const int jg   = wave * 8 + (lane >> 3);   // channel group 0..63

    const f2* r0 = reinterpret_cast<const f2*>(Wh + (size_t)(jg +   0) * H_SZ + ks * 32);
    const f2* r1 = reinterpret_cast<const f2*>(Wh + (size_t)(jg +  64) * H_SZ + ks * 32);
    const f2* r2 = reinterpret_cast<const f2*>(Wh + (size_t)(jg + 128) * H_SZ + ks * 32);
    const f2* r3 = reinterpret_cast<const f2*>(Wh + (size_t)(jg + 192) * H_SZ + ks * 32);
    DECLC(0) DECLC(1) DECLC(2) DECLC(3)

    if (tid < H_SZ) {
        hs[0][(tid >> 5) * SLICE_W + (tid & 31)] = h0[(size_t)b * H_SZ + tid];
    }
    __syncthreads();

    float* __restrict__ outb = out + (size_t)b * H_SZ;
    const size_t tstr = (size_t)B_SZ * H_SZ;

    // Prologue: set A = slab 0 (even steps), set B = slab 1 (odd steps).
    float xa0 = outb[jg +   0];
    float xa1 = outb[jg +  64];
    float xa2 = outb[jg + 128];
    float xa3 = outb[jg + 192];
    float xb0 = outb[tstr + jg +   0];
    float xb1 = outb[tstr + jg +  64];
    float xb2 = outb[tstr + jg + 128];
    float xb3 = outb[tstr + jg + 192];

    float hn0 = 0.f, hn1 = 0.f, hn2 = 0.f, hn3 = 0.f;
    for (int t = 0; t < L_SEQ; t += 2) {
        BODY(t,     0, 1, xa0, xa1, xa2, xa3)
        BODY(t + 1, 1, 0, xb0, xb1, xb2, xb3)
    }

    if (ks == 0) {
        float* hf = out + (size_t)L_SEQ * tstr + (size_t)b * H_SZ;
        hf[jg +   0] = hn0;
        hf[jg +  64] = hn1;
        hf[jg + 128] = hn2;
        hf[jg + 192] = hn3;
    }
}

extern "C" void kernel_launch(void* const* d_in, const int* in_sizes, int n_in,
                              void* d_out, int out_size, void* d_ws, size_t ws_size,
                              hipStream_t stream) {
    const float* x    = (const float*)d_in[0];   // [L,B,D]
    const float* h0   = (const float*)d_in[1];   // [B,H]
    const float* Wx_w = (const float*)d_in[2];   // [H,D]
    const float* Wx_b = (const float*)d_in[3];   // [H]
    const float* Wh_w = (const float*)d_in[4];   // [H,H]
    const float* Wh_b = (const float*)d_in[5];   // [H]
    float* out = (float*)d_out;                  // [L,B,H] ++ [B,H]

    (void)in_sizes; (void)n_in; (void)d_ws; (void)ws_size; (void)out_size;

    dim3 grid1((L_SEQ * B_SZ) / 128, H_SZ / 128);
    xproj_gemm<<<grid1, 256, 0, stream>>>(x, Wx_w, Wx_b, Wh_b, out);

    rnn_scan<<<dim3(B_SZ), 512, 0, stream>>>(h0, Wh_w, out);
}